// Round 5
// baseline (341.989 us; speedup 1.0000x reference)
//
#include <hip/hip_runtime.h>
#include <stdint.h>

#define S_LEN 2048
#define NH 16
#define NG 8
#define HDIM 128

typedef __bf16 bf16x8 __attribute__((ext_vector_type(8)));
typedef __bf16 bf16x4v __attribute__((ext_vector_type(4)));
typedef float f32x4 __attribute__((ext_vector_type(4)));

#define MFMA16(a, b, c) __builtin_amdgcn_mfma_f32_16x16x32_bf16((a), (b), (c), 0, 0, 0)

__device__ __forceinline__ uint16_t f2bf(float f) {
  union { float f; uint32_t u; } v; v.f = f;
  return (uint16_t)((v.u + 0x7fffu + ((v.u >> 16) & 1u)) >> 16);
}

__device__ __forceinline__ void gload16(const void* g, void* l) {
  __builtin_amdgcn_global_load_lds(
      (__attribute__((address_space(1))) const void*)g,
      (__attribute__((address_space(3))) void*)l, 16, 0, 0);
}

// ---------------- x -> bf16 ----------------
__global__ __launch_bounds__(256) void cvt_x_kernel(
    const float* __restrict__ x, uint16_t* __restrict__ xb, int n4) {
  int i = blockIdx.x * 256 + threadIdx.x;
  if (i >= n4) return;
  float4 v = ((const float4*)x)[i];
  ushort4 o;
  o.x = f2bf(v.x); o.y = f2bf(v.y); o.z = f2bf(v.z); o.w = f2bf(v.w);
  ((ushort4*)xb)[i] = o;
}

// ---------------- W[k][n] f32 -> dst[n][k] bf16 ----------------
__global__ __launch_bounds__(256) void trans_cvt_kernel(
    const float* __restrict__ src, uint16_t* __restrict__ dst, int K, int N) {
  __shared__ float T[32][33];
  int n0 = blockIdx.x * 32, k0 = blockIdx.y * 32;
  int tx = threadIdx.x & 31, ty = threadIdx.x >> 5;  // 32 x 8
  #pragma unroll
  for (int i = 0; i < 4; ++i)
    T[ty + i * 8][tx] = src[(size_t)(k0 + ty + i * 8) * N + n0 + tx];
  __syncthreads();
  #pragma unroll
  for (int i = 0; i < 4; ++i)
    dst[(size_t)(n0 + ty + i * 8) * K + k0 + tx] = f2bf(T[tx][ty + i * 8]);
}

// ================= pipelined GEMM: 2 phases / K-tile, counted vmcnt =========
// C[M][N] f32 = A[M][K]bf16 @ BT[N][K]bf16. Tile BM x 256, BK=64, 8 waves
// (2M x 4N), 512 threads. K-tile split in two K=32 halves; 8 LDS slots
// (A/B x parity x khalf). Per phase: {vmcnt(counted); barrier; issue gloads;
// 12 ds_read_b128; 32 MFMA}. Issue slots: P0(u)->k1(u+1), P1(u)->k0(u+2);
// steady wait 2*(LA+2) lands the needed half, 2 newest halves stay in
// flight. All swizzle/global addresses precomputed (const-indexed).
// Swizzled half layout (row = 32 bf16 = 64B): byte = pair*128 + slot'*16,
// pair=row>>1, slot=(row&1)*4+c, slot'=slot^(pair&7). Verified 2-way max
// bank aliasing (free) and measured SQ_LDS_BANK_CONFLICT==0.
#define BAR() asm volatile("s_barrier" ::: "memory")

template <int BM>
__global__ __launch_bounds__(512, 2) void gemm8p_kernel(
    const uint16_t* __restrict__ A, const uint16_t* __restrict__ BT,
    float* __restrict__ C, int M, int N, int K, int gridN) {
  extern __shared__ char smem[];
  constexpr int MI = BM / 32;       // m-frags per wave (8 or 4)
  constexpr int LA = BM / 128;      // A gloads/thread per half (2 or 1)
  constexpr int ABYTES = BM * 64;   // bytes per A-half
  constexpr int BOFF = 4 * ABYTES;  // B region base
  const int tid = threadIdx.x, lane = tid & 63;
  const int wid = tid >> 6;
  const int l15 = lane & 15, l4 = lane >> 4;
  const int wm = wid >> 2, wn = wid & 3;

  // XCD-aware swizzle (grid is a multiple of 8)
  const int nwg = gridDim.x, bid = blockIdx.x;
  const int cpx = nwg >> 3;
  const int swz = (bid & 7) * cpx + (bid >> 3);
  const int m0 = (swz / gridN) * BM, n0 = (swz % gridN) * 256;

  const uint16_t* Ag = A + (size_t)m0 * K;
  const uint16_t* Bg = BT + (size_t)n0 * K;
  const int NT = K >> 6;

  // ---- precomputed staging addresses (loop-invariant) ----
  size_t gAo[LA]; int lAo[LA];
  #pragma unroll
  for (int i = 0; i < LA; ++i) {
    int ch = i * 512 + tid;
    int pair = ch >> 3, slotd = ch & 7;
    int slotl = slotd ^ (pair & 7);
    int row = pair * 2 + (slotl >> 2), c2 = slotl & 3;
    gAo[i] = (size_t)row * K + c2 * 8;
    lAo[i] = ch * 16;
  }
  size_t gBo[2]; int lBo[2];
  #pragma unroll
  for (int i = 0; i < 2; ++i) {
    int ch = i * 512 + tid;
    int pair = ch >> 3, slotd = ch & 7;
    int slotl = slotd ^ (pair & 7);
    int row = pair * 2 + (slotl >> 2), c2 = slotl & 3;
    gBo[i] = (size_t)row * K + c2 * 8;
    lBo[i] = ch * 16;
  }
  // ---- precomputed fragment read offsets ----
  const int arow = wm * (BM / 2) + l15;
  int aoff[MI];
  #pragma unroll
  for (int mi = 0; mi < MI; ++mi) {
    int r = arow + mi * 16;
    int pair = r >> 1, slot = ((r & 1) << 2) | l4;
    aoff[mi] = pair * 128 + ((slot ^ (pair & 7)) * 16);
  }
  int boff[4];
  #pragma unroll
  for (int ni = 0; ni < 4; ++ni) {
    int r = wn * 64 + ni * 16 + l15;
    int pair = r >> 1, slot = ((r & 1) << 2) | l4;
    boff[ni] = pair * 128 + ((slot ^ (pair & 7)) * 16);
  }

#define STAGE_A(koff, slot)                                                   \
  do {                                                                        \
    _Pragma("unroll")                                                         \
    for (int i_ = 0; i_ < LA; ++i_)                                           \
      gload16(Ag + gAo[i_] + (koff), smem + (slot)*ABYTES + lAo[i_]);         \
  } while (0)
#define STAGE_B(koff, slot)                                                   \
  do {                                                                        \
    _Pragma("unroll")                                                         \
    for (int i_ = 0; i_ < 2; ++i_)                                            \
      gload16(Bg + gBo[i_] + (koff), smem + BOFF + (slot)*16384 + lBo[i_]);   \
  } while (0)
// steady wait = 2*(LA+2); tail P0 = LA+2; tail P1 = 0
#define WAIT_STEADY()                                                         \
  do { if constexpr (BM == 256) asm volatile("s_waitcnt vmcnt(8)" ::: "memory"); \
       else                     asm volatile("s_waitcnt vmcnt(6)" ::: "memory"); } while (0)
#define WAIT_TAIL0()                                                          \
  do { if constexpr (BM == 256) asm volatile("s_waitcnt vmcnt(4)" ::: "memory"); \
       else                     asm volatile("s_waitcnt vmcnt(3)" ::: "memory"); } while (0)

  f32x4 acc[MI][4];
  #pragma unroll
  for (int mi = 0; mi < MI; ++mi)
    #pragma unroll
    for (int ni = 0; ni < 4; ++ni) acc[mi][ni] = (f32x4){0.f, 0.f, 0.f, 0.f};

  // prologue: k0(0)->slot0, k1(0)->slot1, k0(1)->slot2   [slot = 2*par+kh]
  STAGE_A(0, 0);  STAGE_B(0, 0);
  STAGE_A(32, 1); STAGE_B(32, 1);
  STAGE_A(64, 2); STAGE_B(64, 2);

  int par = 0;
  for (int u = 0; u < NT; ++u, par ^= 1) {
    const int kb = u * 64;
    bf16x8 af[MI], bfr[4];
    // ---- P0: k-sub 0 (reads slot(par,0)) ----
    if (u == NT - 1) WAIT_TAIL0(); else WAIT_STEADY();
    BAR();
    if (u + 1 < NT) {  // issue k1(u+1) -> slot(par^1,1)
      STAGE_A(kb + 96, 2 * (par ^ 1) + 1);
      STAGE_B(kb + 96, 2 * (par ^ 1) + 1);
    }
    {
      const char* Ab = smem + (2 * par + 0) * ABYTES;
      const char* Bb = smem + BOFF + (2 * par + 0) * 16384;
      #pragma unroll
      for (int mi = 0; mi < MI; ++mi) af[mi] = *(const bf16x8*)(Ab + aoff[mi]);
      #pragma unroll
      for (int ni = 0; ni < 4; ++ni) bfr[ni] = *(const bf16x8*)(Bb + boff[ni]);
    }
    __builtin_amdgcn_s_setprio(1);
    #pragma unroll
    for (int mi = 0; mi < MI; ++mi)
      #pragma unroll
      for (int ni = 0; ni < 4; ++ni)
        acc[mi][ni] = MFMA16(af[mi], bfr[ni], acc[mi][ni]);
    __builtin_amdgcn_s_setprio(0);
    // ---- P1: k-sub 1 (reads slot(par,1)) ----
    if (u == NT - 1) asm volatile("s_waitcnt vmcnt(0)" ::: "memory");
    else WAIT_STEADY();
    BAR();
    if (u + 2 < NT) {  // issue k0(u+2) -> slot(par,0)
      STAGE_A(kb + 128, 2 * par + 0);
      STAGE_B(kb + 128, 2 * par + 0);
    }
    {
      const char* Ab = smem + (2 * par + 1) * ABYTES;
      const char* Bb = smem + BOFF + (2 * par + 1) * 16384;
      #pragma unroll
      for (int mi = 0; mi < MI; ++mi) af[mi] = *(const bf16x8*)(Ab + aoff[mi]);
      #pragma unroll
      for (int ni = 0; ni < 4; ++ni) bfr[ni] = *(const bf16x8*)(Bb + boff[ni]);
    }
    __builtin_amdgcn_s_setprio(1);
    #pragma unroll
    for (int mi = 0; mi < MI; ++mi)
      #pragma unroll
      for (int ni = 0; ni < 4; ++ni)
        acc[mi][ni] = MFMA16(af[mi], bfr[ni], acc[mi][ni]);
    __builtin_amdgcn_s_setprio(0);
  }

  #pragma unroll
  for (int mi = 0; mi < MI; ++mi)
    #pragma unroll
    for (int ni = 0; ni < 4; ++ni) {
      float* dst = C + (size_t)(m0 + wm * (BM / 2) + mi * 16 + l4 * 4) * N +
                   n0 + wn * 64 + ni * 16 + l15;
      #pragma unroll
      for (int r = 0; r < 4; ++r) dst[(size_t)r * N] = acc[mi][ni][r];
    }
#undef STAGE_A
#undef STAGE_B
#undef WAIT_STEADY
#undef WAIT_TAIL0
}

// ---------------- RMSNorm + RoPE for Q and K (wave per row-head) ----------------
__global__ __launch_bounds__(256) void qk_rope_kernel(
    const float* __restrict__ QKV, const float* __restrict__ cosb,
    const float* __restrict__ sinb, const float* __restrict__ qs,
    const float* __restrict__ ks, uint16_t* __restrict__ Qb,
    uint16_t* __restrict__ Kb) {
  const int task = blockIdx.x * 4 + (threadIdx.x >> 6);
  const int lane = threadIdx.x & 63;
  const int hh = task % 24;
  const int row = task / 24;
  const int s = row & (S_LEN - 1);
  const int b = row >> 11;
  const float c1 = cosb[s * 128 + lane], c2 = cosb[s * 128 + 64 + lane];
  const float s1 = sinb[s * 128 + lane], s2 = sinb[s * 128 + 64 + lane];
  const float* src = QKV + (size_t)row * 4096;
  float v1, v2, sc1, sc2, outscale;
  uint16_t* dst;
  if (hh < 16) {
    v1 = src[hh * 128 + lane]; v2 = src[hh * 128 + 64 + lane];
    sc1 = qs[lane]; sc2 = qs[lane + 64];
    outscale = 0.088388347648318447f;  // 1/sqrt(HD), folded softmax scale
    dst = Qb + ((size_t)(b * NH + hh) * S_LEN + s) * 128;
  } else {
    int g = hh - 16;
    v1 = src[2048 + g * 128 + lane]; v2 = src[2048 + g * 128 + 64 + lane];
    sc1 = ks[lane]; sc2 = ks[lane + 64];
    outscale = 1.0f;
    dst = Kb + ((size_t)(b * NG + g) * S_LEN + s) * 128;
  }
  float ss = v1 * v1 + v2 * v2;
  #pragma unroll
  for (int o = 1; o < 64; o <<= 1) ss += __shfl_xor(ss, o);
  float inv = rsqrtf(ss * (1.0f / 128.0f) + 1e-6f);
  float n1 = v1 * inv * sc1, n2 = v2 * inv * sc2;
  dst[lane] = f2bf((n1 * c1 - n2 * s1) * outscale);
  dst[lane + 64] = f2bf((n2 * c2 + n1 * s2) * outscale);
}

// ---------------- V f32 -> V_T[bg][128][S] bf16 ----------------
__global__ __launch_bounds__(256) void v_trans_kernel(
    const float* __restrict__ QKV, uint16_t* __restrict__ Vt) {
  __shared__ uint16_t T[128][72];
  const int s0 = blockIdx.x * 64;
  const int bg = blockIdx.y;
  const int b = bg >> 3, g = bg & 7;
  const int tid = threadIdx.x;
  const int tc = tid & 127, tr = tid >> 7;
  const float* src = QKV + ((size_t)(b * S_LEN + s0)) * 4096 + 3072 + g * 128;
  #pragma unroll
  for (int i = 0; i < 32; ++i) {
    int r = i * 2 + tr;
    T[tc][r] = f2bf(src[(size_t)r * 4096 + tc]);
  }
  __syncthreads();
  uint16_t* dst = Vt + (size_t)bg * 128 * S_LEN + s0;
  #pragma unroll
  for (int i = 0; i < 32; ++i) {
    int idx = i * 256 + tid;
    int d = idx >> 6, sof = idx & 63;
    dst[(size_t)d * S_LEN + sof] = T[d][sof];
  }
}

// ---------------- flash attention (round-4 structure, unchanged) ----------------
__global__ __launch_bounds__(512) void attn_kernel(
    const uint16_t* __restrict__ Qb, const uint16_t* __restrict__ Kb,
    const uint16_t* __restrict__ Vt, uint16_t* __restrict__ Ctx) {
  __shared__ uint8_t smem[65536 + 8 * 2304];
  const int tid = threadIdx.x, lane = tid & 63, wid = tid >> 6;
  uint16_t* Ps = (uint16_t*)(smem + 65536) + wid * 1152;  // [16][72] per wave
  const int l15 = lane & 15, l4 = lane >> 4;

  const int bg = blockIdx.y;           // b*8 + g
  const int b = bg >> 3, g = bg & 7;
  const int h = (g << 1) | (wid >> 2); // wave's head within the group
  const int bh = b * NH + h;

  const uint16_t* Qh = Qb + (size_t)bh * S_LEN * HDIM;
  const uint16_t* Kh = Kb + (size_t)bg * S_LEN * HDIM;
  const uint16_t* Vh = Vt + (size_t)bg * HDIM * S_LEN;

  const int k_row = lane >> 4, k_c = lane & 15;  // K chunk: 4 rows x 256B
  const int v_row = lane >> 3, v_c = lane & 7;   // V chunk: 8 rows x 128B

#define STAGE(kt_, buf_)                                                      \
  do {                                                                        \
    const int kv0_ = (kt_) * 64;                                              \
    uint16_t* KsB_ = (uint16_t*)(smem + (buf_) * 16384);                      \
    uint16_t* VsB_ = (uint16_t*)(smem + 32768 + (buf_) * 16384);              \
    _Pragma("unroll")                                                         \
    for (int i_ = 0; i_ < 2; ++i_) {                                          \
      int chunk_ = wid * 2 + i_;                                              \
      int row_ = chunk_ * 4 + k_row;                                          \
      int sc_ = (k_c ^ (row_ & 7)) * 8;                                       \
      gload16(Kh + (size_t)(kv0_ + row_) * HDIM + sc_, KsB_ + chunk_ * 512);  \
    }                                                                         \
    _Pragma("unroll")                                                         \
    for (int i_ = 0; i_ < 2; ++i_) {                                          \
      int chunk_ = wid * 2 + i_;                                              \
      int row_ = chunk_ * 8 + v_row;                                          \
      int sc_ = (v_c ^ (row_ & 7)) * 8;                                       \
      gload16(Vh + (size_t)row_ * S_LEN + kv0_ + sc_, VsB_ + chunk_ * 512);   \
    }                                                                         \
  } while (0)

  for (int half = 0; half < 2; ++half) {
    const int qtile = half ? (31 - (int)blockIdx.x) : (int)blockIdx.x;
    const int q0 = qtile * 64;
    const int qrow = q0 + (wid & 3) * 16 + l15;

    bf16x8 qf[4];
    #pragma unroll
    for (int kk = 0; kk < 4; ++kk)
      qf[kk] = *(const bf16x8*)(Qh + (size_t)qrow * HDIM + kk * 32 + l4 * 8);

    f32x4 acc[8];
    #pragma unroll
    for (int i = 0; i < 8; ++i) acc[i] = (f32x4){0.f, 0.f, 0.f, 0.f};
    float mrun = -1e30f, lrun = 0.f;

    const int nt = qtile + 1;
    int cur = 0;
    STAGE(0, 0);
    asm volatile("s_waitcnt vmcnt(0)\ns_barrier" ::: "memory");

    for (int kt = 0; kt < nt; ++kt) {
      const int kv0 = kt * 64;
      if (kt + 1 < nt) STAGE(kt + 1, cur ^ 1);

      uint16_t* Ks = (uint16_t*)(smem + cur * 16384);
      uint16_t* Vs = (uint16_t*)(smem + 32768 + cur * 16384);

      // S^T[key][qrow] = K @ Q^T (lane owns q-row = l15)
      f32x4 sc[4];
      #pragma unroll
      for (int i = 0; i < 4; ++i) sc[i] = (f32x4){0.f, 0.f, 0.f, 0.f};
      __builtin_amdgcn_s_setprio(1);
      #pragma unroll
      for (int kk = 0; kk < 4; ++kk) {
        #pragma unroll
        for (int kc = 0; kc < 4; ++kc) {
          int key = kc * 16 + l15;
          int cc = (kk * 4 + l4) ^ (key & 7);
          bf16x8 kf = *(const bf16x8*)(Ks + key * 128 + cc * 8);
          sc[kc] = MFMA16(kf, qf[kk], sc[kc]);
        }
      }
      __builtin_amdgcn_s_setprio(0);
      if (kt == nt - 1) {  // diagonal tile: causal mask
        #pragma unroll
        for (int kc = 0; kc < 4; ++kc)
          #pragma unroll
          for (int r = 0; r < 4; ++r)
            if (kv0 + kc * 16 + l4 * 4 + r > qrow) sc[kc][r] = -1e30f;
      }
      float tmax = -1e30f;
      #pragma unroll
      for (int kc = 0; kc < 4; ++kc)
        #pragma unroll
        for (int r = 0; r < 4; ++r) tmax = fmaxf(tmax, sc[kc][r]);
      tmax = fmaxf(tmax, __shfl_xor(tmax, 16));
      tmax = fmaxf(tmax, __shfl_xor(tmax, 32));
      // T13 defer-max: only rescale when the max actually grows by >8
      if (!__all(tmax <= mrun + 8.0f)) {
        float mnew = fmaxf(mrun, tmax);
        float corr = __expf(mrun - mnew);
        lrun *= corr;
        #pragma unroll
        for (int d0 = 0; d0 < 8; ++d0) acc[d0] *= corr;
        mrun = mnew;
      }
      float tsum = 0.f;
      #pragma unroll
      for (int kc = 0; kc < 4; ++kc) {
        float p0 = __expf(sc[kc][0] - mrun);
        float p1 = __expf(sc[kc][1] - mrun);
        float p2 = __expf(sc[kc][2] - mrun);
        float p3 = __expf(sc[kc][3] - mrun);
        tsum += (p0 + p1) + (p2 + p3);
        bf16x4v pw = {(__bf16)p0, (__bf16)p1, (__bf16)p2, (__bf16)p3};
        *(bf16x4v*)(Ps + l15 * 72 + kc * 16 + l4 * 4) = pw;
      }
      tsum += __shfl_xor(tsum, 16);
      tsum += __shfl_xor(tsum, 32);
      lrun += tsum;

      // ctx^T[d][qrow] += V^T @ P^T
      __builtin_amdgcn_s_setprio(1);
      #pragma unroll
      for (int hf = 0; hf < 2; ++hf) {
        bf16x8 pf = *(const bf16x8*)(Ps + l15 * 72 + hf * 32 + l4 * 8);
        #pragma unroll
        for (int d0 = 0; d0 < 8; ++d0) {
          int d = d0 * 16 + l15;
          int cc = (hf * 4 + l4) ^ (d & 7);
          bf16x8 vf = *(const bf16x8*)(Vs + d * 64 + cc * 8);
          acc[d0] = MFMA16(vf, pf, acc[d0]);
        }
      }
      __builtin_amdgcn_s_setprio(0);

      asm volatile("s_waitcnt vmcnt(0)\ns_barrier" ::: "memory");
      cur ^= 1;
    }

    float inv = 1.0f / lrun;
    uint16_t* dst = Ctx + ((size_t)(b * S_LEN + qrow) * NH + h) * HDIM;
    #pragma unroll
    for (int d0 = 0; d0 < 8; ++d0) {
      bf16x4v o = {(__bf16)(acc[d0][0] * inv), (__bf16)(acc[d0][1] * inv),
                   (__bf16)(acc[d0][2] * inv), (__bf16)(acc[d0][3] * inv)};
      *(bf16x4v*)(dst + d0 * 16 + l4 * 4) = o;
    }
  }
#undef STAGE
}

extern "C" void kernel_launch(void* const* d_in, const int* in_sizes, int n_in,
                              void* d_out, int out_size, void* d_ws, size_t ws_size,
                              hipStream_t stream) {
  const float* x    = (const float*)d_in[0];
  const float* cosb = (const float*)d_in[2];
  const float* sinb = (const float*)d_in[3];
  const float* Wq   = (const float*)d_in[4];
  const float* Wk   = (const float*)d_in[5];
  const float* Wv   = (const float*)d_in[6];
  const float* Wo   = (const float*)d_in[7];
  const float* qs   = (const float*)d_in[8];
  const float* ks   = (const float*)d_in[9];

  char* ws = (char*)d_ws;
  uint16_t* Xb    = (uint16_t*)(ws);                         // 16 MB  [4096][2048]
  uint16_t* WallT = (uint16_t*)(ws + (16ull << 20));         // 16 MB  [4096][2048]
  uint16_t* WoT   = (uint16_t*)(ws + (32ull << 20));         //  8 MB  [2048][2048]
  float*    QKV   = (float*)   (ws + (40ull << 20));         // 64 MB  [4096][4096]
  uint16_t* Qb    = (uint16_t*)(ws + (104ull << 20));        // 16 MB  [B*H][S][128]
  uint16_t* Kb    = (uint16_t*)(ws + (120ull << 20));        //  8 MB  [B*G][S][128]
  uint16_t* Vt    = (uint16_t*)(ws + (128ull << 20));        //  8 MB  [B*G][128][S]
  uint16_t* Ctx   = (uint16_t*)(ws + (136ull << 20));        // 16 MB  [4096][2048]
  float* out = (float*)d_out;

  hipFuncSetAttribute(reinterpret_cast<const void*>(&gemm8p_kernel<256>),
                      hipFuncAttributeMaxDynamicSharedMemorySize, 131072);
  hipFuncSetAttribute(reinterpret_cast<const void*>(&gemm8p_kernel<128>),
                      hipFuncAttributeMaxDynamicSharedMemorySize, 98304);

  cvt_x_kernel<<<8192, 256, 0, stream>>>(x, Xb, 2097152);
  trans_cvt_kernel<<<dim3(64, 64), 256, 0, stream>>>(Wq, WallT, 2048, 2048);
  trans_cvt_kernel<<<dim3(32, 64), 256, 0, stream>>>(Wk, WallT + 2048 * 2048, 2048, 1024);
  trans_cvt_kernel<<<dim3(32, 64), 256, 0, stream>>>(Wv, WallT + 3072 * 2048, 2048, 1024);
  trans_cvt_kernel<<<dim3(64, 64), 256, 0, stream>>>(Wo, WoT, 2048, 2048);
  gemm8p_kernel<256><<<256, 512, 131072, stream>>>(Xb, WallT, QKV, 4096, 4096, 2048, 16);
  qk_rope_kernel<<<24576, 256, 0, stream>>>(QKV, cosb, sinb, qs, ks, Qb, Kb);
  v_trans_kernel<<<dim3(32, 16), 256, 0, stream>>>(QKV, Vt);
  attn_kernel<<<dim3(16, 16), 512, 0, stream>>>(Qb, Kb, Vt, Ctx);
  gemm8p_kernel<128><<<256, 512, 98304, stream>>>(Ctx, WoT, out, 4096, 2048, 2048, 8);
}